// Round 12
// baseline (565.755 us; speedup 1.0000x reference)
//
#include <hip/hip_runtime.h>
#include <cstdint>
#include <cstddef>

#define NN 50000
#define EE 800000
#define CAP 64
#define EPS_BN 1e-5f

typedef short  s16x8 __attribute__((ext_vector_type(8)));
typedef ushort u16x8 __attribute__((ext_vector_type(8)));
typedef float  f32x4 __attribute__((ext_vector_type(4)));

#define MFMA16(a, b, c) __builtin_amdgcn_mfma_f32_16x16x32_bf16((a), (b), (c), 0, 0, 0)

__device__ inline ushort f2bf(float f){           // round-to-nearest-even fp32->bf16
  uint32_t u = __float_as_uint(f);
  uint32_t r = (u + 0x7FFFu + ((u >> 16) & 1u)) >> 16;
  return (ushort)r;
}
__device__ inline float bf2f(ushort u){ return __uint_as_float((uint32_t)u << 16); }

// ---------------- graph preprocessing (single edge pass) ----------------

__global__ void k_prep(const int* __restrict__ row, const int* __restrict__ col,
                       int* __restrict__ outdeg, int* __restrict__ incnt,
                       ushort* __restrict__ bsrc16){
  int e = blockIdx.x * blockDim.x + threadIdx.x;
  if (e >= EE) return;
  int r = row[e], c = col[e];
  atomicAdd(&outdeg[r], 1);
  int j = atomicAdd(&incnt[c], 1);
  if (j < CAP) bsrc16[(size_t)c * CAP + j] = (ushort)r;
}

// ---------------- fp32 -> bf16 bulk convert ----------------

__global__ void k_cvt(const float* __restrict__ src, ushort* __restrict__ dst, int n4){
  int i = blockIdx.x * blockDim.x + threadIdx.x;
  int stride = gridDim.x * blockDim.x;
  for (; i < n4; i += stride){
    float4 v = ((const float4*)src)[i];
    ushort4 u = {f2bf(v.x), f2bf(v.y), f2bf(v.z), f2bf(v.w)};
    ((ushort4*)dst)[i] = u;
  }
}

// ------- weight conversion: fp32 [K x NF] -> bf16 MFMA-fragment order -------
// dst[((ct*P + p)*2 + ks)*512 + lane*8 + j] = W[k][col]
//   col = ct*16 + (lane&15),  k = p*64 + ks*32 + (lane>>4)*8 + j
// mode: 0 = single src; 1 = k-split at splitVal (srcB rows); 2 = col-split.

struct FJob { const float* srcA; const float* srcB; ushort* dst;
              int NF; int NCT; int P; int mode; int splitVal; };
struct FJobs { FJob j[10]; };

__global__ void k_conv(FJobs J){
  FJob jb = J.j[blockIdx.x];
  int total = jb.NCT * jb.P * 1024;
  for (int idx = threadIdx.x + blockIdx.y * 256; idx < total; idx += 256 * gridDim.y){
    int j = idx & 7, lane = (idx >> 3) & 63, ks = (idx >> 9) & 1;
    int rest = idx >> 10;
    int p = rest % jb.P, ct = rest / jb.P;
    int col = ct * 16 + (lane & 15);
    int k   = p * 64 + ks * 32 + (lane >> 4) * 8 + j;
    const float* s = jb.srcA;
    int sc = col, sk = k;
    if (jb.mode == 1 && k   >= jb.splitVal){ s = jb.srcB; sk = k   - jb.splitVal; }
    if (jb.mode == 2 && col >= jb.splitVal){ s = jb.srcB; sc = col - jb.splitVal; }
    jb.dst[idx] = f2bf(s[(size_t)sk * jb.NF + sc]);
  }
}

// ------- standalone aggregation (path steps): out[c] = sum_e w_e*hin[src_e] ------
// wave per node; 8 lanes x 16B per source row; 16 edges in flight per iter.
// weights: use_norm ? 1/outdeg[src] : 1/cnt

__global__ void __launch_bounds__(256) k_agg(const ushort* __restrict__ hin,
                                             ushort* __restrict__ out,
                                             const ushort* __restrict__ bsrc16,
                                             const int* __restrict__ outdeg,
                                             const int* __restrict__ incnt,
                                             int use_norm){
  __shared__ int   sidx[4][CAP + 16];
  __shared__ float swgt[4][CAP + 16];
  int wib  = threadIdx.x >> 6;
  int lane = threadIdx.x & 63;
  int wid  = blockIdx.x * 4 + wib;
  bool valid = wid < NN;
  int cnt  = valid ? incnt[wid] : 0;
  int cntb = min(cnt, CAP);
  if (valid){
    int src = (lane < cntb) ? (int)bsrc16[(size_t)wid * CAP + lane] : 0;
    float w = 0.f;
    if (lane < cntb)
      w = use_norm ? (1.0f / fmaxf((float)outdeg[src], 1.f))
                   : (1.0f / fmaxf((float)cnt, 1.f));
    sidx[wib][lane] = src;
    swgt[wib][lane] = w;
    if (lane < 16){ sidx[wib][CAP + lane] = 0; swgt[wib][CAP + lane] = 0.f; }
  }
  __syncthreads();
  if (!valid) return;

  int g  = lane >> 3;
  int fl = lane & 7;
  float accf[8] = {0,0,0,0,0,0,0,0};
  for (int e0 = 0; e0 < cntb; e0 += 16){
    int ea = e0 + g, eb = e0 + g + 8;
    int   sa = sidx[wib][ea], sb = sidx[wib][eb];
    float wa = swgt[wib][ea], wb = swgt[wib][eb];
    u16x8 va = *(const u16x8*)(hin + (size_t)sa * 64 + fl * 8);
    u16x8 vb = *(const u16x8*)(hin + (size_t)sb * 64 + fl * 8);
    #pragma unroll
    for (int j = 0; j < 8; ++j){
      accf[j] = fmaf(wa, bf2f(va[j]), accf[j]);
      accf[j] = fmaf(wb, bf2f(vb[j]), accf[j]);
    }
  }
  #pragma unroll
  for (int m = 8; m < 64; m <<= 1){
    #pragma unroll
    for (int j = 0; j < 8; ++j) accf[j] += __shfl_xor(accf[j], m);
  }
  if (lane < 8){
    u16x8 o;
    #pragma unroll
    for (int j = 0; j < 8; ++j) o[j] = f2bf(accf[j]);
    *(u16x8*)(out + (size_t)wid * 64 + lane * 8) = o;
  }
}

// ---- shared helper: block aggregates mean(hsrc) for its 64 nodes into sMean ----
// sMean layout: row stride 72 ushort (MFMA A-frag ready). Per-wave: 16 nodes.

__device__ inline void block_agg_mean(const ushort* __restrict__ hsrc,
                                      const ushort* __restrict__ bsrc16,
                                      const int* __restrict__ incnt,
                                      int base, ushort* sidx /*[64][CAP+16]*/,
                                      ushort* sMean, float* scw, int* scnt){
  int wib = threadIdx.x >> 6, lane = threadIdx.x & 63;
  #pragma unroll 1
  for (int ni = 0; ni < 16; ++ni){
    int nrow = wib * 16 + ni;
    int node = base + nrow;
    int cnt  = (node < NN) ? incnt[node] : 0;
    int cntb = min(cnt, CAP);
    if (lane == 0){ scnt[nrow] = cntb; scw[nrow] = 1.0f / fmaxf((float)cnt, 1.f); }
    ushort* si = sidx + nrow * (CAP + 16);
    si[lane] = (node < NN && lane < cntb) ? bsrc16[(size_t)node * CAP + lane] : (ushort)0;
    if (lane < 16) si[CAP + lane] = 0;
  }
  int g8 = lane >> 3, fl = lane & 7;
  #pragma unroll 1
  for (int ni = 0; ni < 16; ++ni){
    int nrow = wib * 16 + ni;
    int cntb = scnt[nrow];
    float w  = scw[nrow];
    const ushort* si = sidx + nrow * (CAP + 16);
    float accf[8] = {0,0,0,0,0,0,0,0};
    for (int e0 = 0; e0 < cntb; e0 += 16){
      int ea = e0 + g8, eb = ea + 8;
      int   sa = si[ea], sb = si[eb];
      float wa = (ea < cntb) ? w : 0.f;
      float wb = (eb < cntb) ? w : 0.f;
      u16x8 va = *(const u16x8*)(hsrc + (size_t)sa * 64 + fl * 8);
      u16x8 vb = *(const u16x8*)(hsrc + (size_t)sb * 64 + fl * 8);
      #pragma unroll
      for (int j = 0; j < 8; ++j){
        accf[j] = fmaf(wa, bf2f(va[j]), accf[j]);
        accf[j] = fmaf(wb, bf2f(vb[j]), accf[j]);
      }
    }
    #pragma unroll
    for (int m = 8; m < 64; m <<= 1){
      #pragma unroll
      for (int j = 0; j < 8; ++j) accf[j] += __shfl_xor(accf[j], m);
    }
    if (lane < 8){
      u16x8 o;
      #pragma unroll
      for (int j = 0; j < 8; ++j) o[j] = f2bf(accf[j]);
      *(u16x8*)(sMean + nrow * 72 + lane * 8) = o;
    }
  }
}

// ---- fused sage layer: agg + GEMM + bn/relu/residual ----
__global__ void __launch_bounds__(256) k_sage_f(const ushort* __restrict__ hb,
                                                const ushort* __restrict__ WT,
                                                const ushort* __restrict__ bsrc16,
                                                const int* __restrict__ incnt,
                                                const float* __restrict__ bl,
                                                const float* __restrict__ g,
                                                const float* __restrict__ be,
                                                const float* __restrict__ m_,
                                                const float* __restrict__ var_,
                                                ushort* __restrict__ houtb){
  __shared__ ushort sidx[64 * (CAP + 16)];
  __shared__ __align__(16) ushort sMean[64 * 72];
  __shared__ float scw[64];
  __shared__ int   scnt[64];
  int base = blockIdx.x * 64;
  block_agg_mean(hb, bsrc16, incnt, base, sidx, sMean, scw, scnt);
  __syncthreads();

  int lane = threadIdx.x & 63, wv = threadIdx.x >> 6, q = lane >> 4, r16 = lane & 15;
  int wrow = wv * 16 + r16;
  int ar = base + wrow; ar = (ar < NN) ? ar : (NN - 1);
  const ushort* wl = WT + lane * 8;
  f32x4 acc[4] = {};
  #pragma unroll
  for (int ks = 0; ks < 2; ++ks){
    s16x8 a0 = *(const s16x8*)(sMean + wrow * 72 + ks * 32 + q * 8);   // p=0 mean
    #pragma unroll
    for (int ct = 0; ct < 4; ++ct){
      s16x8 b = *(const s16x8*)(wl + (((ct * 2 + 0) * 2 + ks) << 9));
      acc[ct] = MFMA16(a0, b, acc[ct]);
    }
    s16x8 a1 = *(const s16x8*)(hb + (size_t)ar * 64 + ks * 32 + q * 8); // p=1 h
    #pragma unroll
    for (int ct = 0; ct < 4; ++ct){
      s16x8 b = *(const s16x8*)(wl + (((ct * 2 + 1) * 2 + ks) << 9));
      acc[ct] = MFMA16(a1, b, acc[ct]);
    }
  }
  #pragma unroll
  for (int ct = 0; ct < 4; ++ct){
    int col = ct * 16 + r16;
    float sc = g[col] * rsqrtf(var_[col] + EPS_BN);
    float sh = be[col] - m_[col] * sc;
    float bb = bl[col];
    #pragma unroll
    for (int r = 0; r < 4; ++r){
      int row = base + wv * 16 + q * 4 + r;
      if (row < NN){
        float t = (acc[ct][r] + bb) * sc + sh;
        float hv = bf2f(hb[(size_t)row * 64 + col]);
        houtb[(size_t)row * 64 + col] = f2bf(fmaxf(t, 0.f) + hv);
      }
    }
  }
}

// ---------------- direct-load MFMA GEMM (no LDS, no barriers) ----------------

template<int P, int NCT>
__device__ inline void gemm_direct(const ushort* const* pieces,
                                   const ushort* __restrict__ WB,
                                   int rowbase, f32x4* acc){
  int lane = threadIdx.x & 63;
  int q = lane >> 4, r16 = lane & 15;
  int ar = rowbase + r16; ar = (ar < NN) ? ar : (NN - 1);
  const ushort* wl = WB + lane * 8;
  #pragma unroll
  for (int p = 0; p < P; ++p){
    const ushort* src = pieces[p] + (size_t)ar * 64 + q * 8;
    #pragma unroll
    for (int ks = 0; ks < 2; ++ks){
      s16x8 a = *(const s16x8*)(src + ks * 32);
      #pragma unroll
      for (int ct = 0; ct < NCT; ++ct){
        s16x8 b = *(const s16x8*)(wl + (((ct * P + p) * 2 + ks) << 9));
        acc[ct] = MFMA16(a, b, acc[ct]);
      }
    }
  }
}

// ---- skip = x @ W_in + b_in  (bf16 out) ----
__global__ void __launch_bounds__(256) k_skip(const ushort* __restrict__ xb,
                                              const ushort* __restrict__ WT,
                                              const float* __restrict__ bias,
                                              ushort* __restrict__ outb){
  int lane = threadIdx.x & 63, wv = threadIdx.x >> 6, q = lane >> 4, r16 = lane & 15;
  int rowbase = blockIdx.x * 64 + wv * 16;
  const ushort* pieces[1] = {xb};
  f32x4 acc[4] = {};
  gemm_direct<1, 4>(pieces, WT, rowbase, acc);
  #pragma unroll
  for (int ct = 0; ct < 4; ++ct){
    int col = ct * 16 + r16;
    float b = bias[col];
    #pragma unroll
    for (int r = 0; r < 4; ++r){
      int row = rowbase + q * 4 + r;
      if (row < NN) outb[(size_t)row * 64 + col] = f2bf(acc[ct][r] + b);
    }
  }
}

// ---- YR: [h1..h4|skip|path](384) @ [vWl|vWr] -> Y, R(+vbl)   (bf16 out) ----
__global__ void __launch_bounds__(256) k_yr(const ushort* __restrict__ x0, const ushort* __restrict__ x1,
                                            const ushort* __restrict__ x2, const ushort* __restrict__ x3,
                                            const ushort* __restrict__ x4, const ushort* __restrict__ x5,
                                            const ushort* __restrict__ WT, const float* __restrict__ vbl,
                                            ushort* __restrict__ Y, ushort* __restrict__ R){
  int lane = threadIdx.x & 63, wv = threadIdx.x >> 6, q = lane >> 4, r16 = lane & 15;
  int rowbase = blockIdx.x * 64 + wv * 16;
  const ushort* pieces[6] = {x0, x1, x2, x3, x4, x5};
  f32x4 acc[8] = {};
  gemm_direct<6, 8>(pieces, WT, rowbase, acc);
  #pragma unroll
  for (int ct = 0; ct < 8; ++ct){
    int col = ct * 16 + r16;
    bool isR = col >= 64;
    int c2 = isR ? (col - 64) : col;
    float b = isR ? vbl[c2] : 0.f;
    ushort* dst = isR ? R : Y;
    #pragma unroll
    for (int r = 0; r < 4; ++r){
      int row = rowbase + q * 4 + r;
      if (row < NN) dst[(size_t)row * 64 + c2] = f2bf(acc[ct][r] + b);
    }
  }
}

// ---- fused mulv: agg(Y) in LDS; v = relu(bn(mean+R)); [mu|lv] = v@[Wmu|Wlv]+b ----
__global__ void __launch_bounds__(256) k_mulv_f(const ushort* __restrict__ Yb,
                                                const ushort* __restrict__ Rb,
                                                const ushort* __restrict__ bsrc16,
                                                const int* __restrict__ incnt,
                                                const float* __restrict__ vg,
                                                const float* __restrict__ vbe,
                                                const float* __restrict__ vm,
                                                const float* __restrict__ vvar,
                                                const ushort* __restrict__ WT,
                                                const float* __restrict__ bmu,
                                                const float* __restrict__ blv,
                                                float* __restrict__ muf, float* __restrict__ lvf,
                                                ushort* __restrict__ mub){
  __shared__ ushort sidx[64 * (CAP + 16)];
  __shared__ __align__(16) ushort sMean[64 * 72];
  __shared__ float scw[64];
  __shared__ int   scnt[64];
  __shared__ float ssc[64], ssh[64];
  int t = threadIdx.x;
  if (t < 64){
    float sc = vg[t] * rsqrtf(vvar[t] + EPS_BN);
    ssc[t] = sc; ssh[t] = vbe[t] - vm[t] * sc;
  }
  int base = blockIdx.x * 64;
  block_agg_mean(Yb, bsrc16, incnt, base, sidx, sMean, scw, scnt);
  __syncthreads();

  int lane = t & 63, wv = t >> 6, q = lane >> 4, r16 = lane & 15;
  int wrow = wv * 16 + r16;
  int ar = base + wrow; ar = (ar < NN) ? ar : (NN - 1);
  const ushort* wl = WT + lane * 8;
  f32x4 acc[8] = {};
  #pragma unroll
  for (int ks = 0; ks < 2; ++ks){
    int k0 = ks * 32 + q * 8;
    u16x8 y  = *(const u16x8*)(sMean + wrow * 72 + k0);
    u16x8 rv = *(const u16x8*)(Rb + (size_t)ar * 64 + k0);
    s16x8 a;
    #pragma unroll
    for (int j = 0; j < 8; ++j){
      float tv = (bf2f(y[j]) + bf2f(rv[j])) * ssc[k0 + j] + ssh[k0 + j];
      a[j] = (short)f2bf(fmaxf(tv, 0.f));
    }
    #pragma unroll
    for (int ct = 0; ct < 8; ++ct){
      s16x8 b = *(const s16x8*)(wl + ((ct * 2 + ks) << 9));
      acc[ct] = MFMA16(a, b, acc[ct]);
    }
  }
  #pragma unroll
  for (int ct = 0; ct < 8; ++ct){
    int col = ct * 16 + r16;
    bool isL = col >= 64;
    int c2 = isL ? (col - 64) : col;
    float bb = isL ? blv[c2] : bmu[c2];
    #pragma unroll
    for (int r = 0; r < 4; ++r){
      int row = base + wv * 16 + q * 4 + r;
      if (row < NN){
        float v = acc[ct][r] + bb;
        if (isL) lvf[(size_t)row * 64 + c2] = v;
        else { muf[(size_t)row * 64 + c2] = v; mub[(size_t)row * 64 + c2] = f2bf(v); }
      }
    }
  }
}

// ---- rank = relu(mu@rW1+rb1) @ rW2 + rb2 ----
__global__ void __launch_bounds__(256) k_rank_m(const ushort* __restrict__ mub,
                                                const ushort* __restrict__ WT,
                                                const float* __restrict__ rb1,
                                                const float* __restrict__ rW2,
                                                const float* __restrict__ rb2,
                                                float* __restrict__ rout){
  int lane = threadIdx.x & 63, wv = threadIdx.x >> 6, q = lane >> 4, r16 = lane & 15;
  int rowbase = blockIdx.x * 64 + wv * 16;
  const ushort* pieces[1] = {mub};
  f32x4 acc[4] = {};
  gemm_direct<1, 4>(pieces, WT, rowbase, acc);
  float val[4] = {0.f, 0.f, 0.f, 0.f};
  #pragma unroll
  for (int ct = 0; ct < 4; ++ct){
    int col = ct * 16 + r16;
    float b1 = rb1[col], w2 = rW2[col];
    #pragma unroll
    for (int r = 0; r < 4; ++r)
      val[r] += fmaxf(acc[ct][r] + b1, 0.f) * w2;
  }
  #pragma unroll
  for (int r = 0; r < 4; ++r){
    #pragma unroll
    for (int m = 1; m < 16; m <<= 1) val[r] += __shfl_xor(val[r], m);
  }
  if (r16 == 0){
    float b2 = rb2[0];
    #pragma unroll
    for (int r = 0; r < 4; ++r){
      int row = rowbase + q * 4 + r;
      if (row < NN) rout[row] = val[r] + b2;
    }
  }
}

// ---- reg stage 1: h1 = relu([stage1|z](384)@gW1[0:384] + gb1 + rank*gW1[384]) ----
__global__ void __launch_bounds__(256) k_reg1(const ushort* __restrict__ x0, const ushort* __restrict__ x1,
                                              const ushort* __restrict__ x2, const ushort* __restrict__ x3,
                                              const ushort* __restrict__ x4, const ushort* __restrict__ x5,
                                              const float* __restrict__ rank,
                                              const ushort* __restrict__ WT,
                                              const float* __restrict__ gW1,   // fp32, for row 384
                                              const float* __restrict__ gb1,
                                              ushort* __restrict__ h1b){
  int lane = threadIdx.x & 63, wv = threadIdx.x >> 6, q = lane >> 4, r16 = lane & 15;
  int rowbase = blockIdx.x * 64 + wv * 16;
  const ushort* pieces[6] = {x0, x1, x2, x3, x4, x5};
  f32x4 acc[4] = {};
  gemm_direct<6, 4>(pieces, WT, rowbase, acc);
  float rk[4];
  #pragma unroll
  for (int r = 0; r < 4; ++r){
    int row = rowbase + q * 4 + r;
    rk[r] = (row < NN) ? rank[row] : 0.f;
  }
  #pragma unroll
  for (int ct = 0; ct < 4; ++ct){
    int col = ct * 16 + r16;
    float b1 = gb1[col];
    float w384 = gW1[384 * 64 + col];
    #pragma unroll
    for (int r = 0; r < 4; ++r){
      int row = rowbase + q * 4 + r;
      if (row < NN)
        h1b[(size_t)row * 64 + col] = f2bf(fmaxf(acc[ct][r] + b1 + rk[r] * w384, 0.f));
    }
  }
}

// ---- reg tail: h2 = relu(h1@gW2+gb2); preds = h2@gW3 + gb3 ----
__global__ void __launch_bounds__(256) k_reg2(const ushort* __restrict__ h1b,
                                              const ushort* __restrict__ WT,
                                              const float* __restrict__ gb2,
                                              const float* __restrict__ gW3,
                                              const float* __restrict__ gb3,
                                              float* __restrict__ preds){
  int lane = threadIdx.x & 63, wv = threadIdx.x >> 6, q = lane >> 4, r16 = lane & 15;
  int rowbase = blockIdx.x * 64 + wv * 16;
  const ushort* pieces[1] = {h1b};
  f32x4 acc[2] = {};
  gemm_direct<1, 2>(pieces, WT, rowbase, acc);
  float val[4] = {0.f, 0.f, 0.f, 0.f};
  #pragma unroll
  for (int ct = 0; ct < 2; ++ct){
    int col = ct * 16 + r16;       // 0..31
    float b2 = gb2[col], w3 = gW3[col];
    #pragma unroll
    for (int r = 0; r < 4; ++r)
      val[r] += fmaxf(acc[ct][r] + b2, 0.f) * w3;
  }
  #pragma unroll
  for (int r = 0; r < 4; ++r){
    #pragma unroll
    for (int m = 1; m < 16; m <<= 1) val[r] += __shfl_xor(val[r], m);
  }
  if (r16 == 0){
    float b3 = gb3[0];
    #pragma unroll
    for (int r = 0; r < 4; ++r){
      int row = rowbase + q * 4 + r;
      if (row < NN) preds[row] = val[r] + b3;
    }
  }
}

// ---------------- launch ----------------

extern "C" void kernel_launch(void* const* d_in, const int* in_sizes, int n_in,
                              void* d_out, int out_size, void* d_ws, size_t ws_size,
                              hipStream_t stream){
  const float* x    = (const float*)d_in[0];
  const int*   eidx = (const int*)d_in[1];
  const int* row = eidx;
  const int* col = eidx + EE;
  const float* W_in = (const float*)d_in[2];
  const float* b_in = (const float*)d_in[3];
  const float* sWl  = (const float*)d_in[4];
  const float* sbl  = (const float*)d_in[5];
  const float* sWr  = (const float*)d_in[6];
  const float* bng  = (const float*)d_in[7];
  const float* bnb  = (const float*)d_in[8];
  const float* bnm  = (const float*)d_in[9];
  const float* bnv  = (const float*)d_in[10];
  const float* vWl  = (const float*)d_in[11];
  const float* vbl  = (const float*)d_in[12];
  const float* vWr  = (const float*)d_in[13];
  const float* vg   = (const float*)d_in[14];
  const float* vbe  = (const float*)d_in[15];
  const float* vm   = (const float*)d_in[16];
  const float* vvar = (const float*)d_in[17];
  const float* Wmu  = (const float*)d_in[18];
  const float* bmu  = (const float*)d_in[19];
  const float* Wlv  = (const float*)d_in[20];
  const float* blv  = (const float*)d_in[21];
  const float* rW1  = (const float*)d_in[22];
  const float* rb1  = (const float*)d_in[23];
  const float* rW2  = (const float*)d_in[24];
  const float* rb2  = (const float*)d_in[25];
  const float* gW1  = (const float*)d_in[26];
  const float* gb1  = (const float*)d_in[27];
  const float* gW2  = (const float*)d_in[28];
  const float* gb2  = (const float*)d_in[29];
  const float* gW3  = (const float*)d_in[30];
  const float* gb3  = (const float*)d_in[31];

  float* preds = (float*)d_out;
  float* rank  = preds + NN;
  float* mu    = rank + NN;
  float* lv    = mu + (size_t)NN * 64;

  char* w = (char*)d_ws;
  auto alloc = [&](size_t bytes) -> char* {
    char* p = w; w += (bytes + 255) & ~(size_t)255; return p;
  };
  int*    outdeg = (int*)alloc((size_t)NN * 4);
  int*    incnt  = (int*)alloc((size_t)NN * 4);
  ushort* bsrc16 = (ushort*)alloc((size_t)NN * CAP * 2);
  const size_t FB = (size_t)NN * 64 * 2;           // bf16 feature buffer
  ushort* xb    = (ushort*)alloc(FB);
  ushort* skipb = (ushort*)alloc(FB);
  ushort* hb[4];
  for (int i = 0; i < 4; ++i) hb[i] = (ushort*)alloc(FB);
  ushort* pa    = (ushort*)alloc(FB);              // path scratch; reused as h1buf
  ushort* pb    = (ushort*)alloc(FB);
  ushort* Yb    = (ushort*)alloc(FB);
  ushort* Rb    = (ushort*)alloc(FB);
  ushort* mub   = (ushort*)alloc(FB);
  ushort* skipW = (ushort*)alloc(4 * 1024 * 2);        // NCT4 P1
  ushort* sageW = (ushort*)alloc(4 * 8 * 1024 * 2);    // 4 layers x NCT4 P2
  ushort* yrW   = (ushort*)alloc(48 * 1024 * 2);       // NCT8 P6
  ushort* mulvW = (ushort*)alloc(8 * 1024 * 2);        // NCT8 P1
  ushort* rankW = (ushort*)alloc(4 * 1024 * 2);        // NCT4 P1
  ushort* regW1 = (ushort*)alloc(24 * 1024 * 2);       // NCT4 P6
  ushort* regW2 = (ushort*)alloc(2 * 1024 * 2);        // NCT2 P1

  hipMemsetAsync(outdeg, 0, (size_t)NN * 4, stream);
  hipMemsetAsync(incnt,  0, (size_t)NN * 4, stream);

  const int EB = (EE + 255) / 256;
  k_prep<<<EB, 256, 0, stream>>>(row, col, outdeg, incnt, bsrc16);

  // weight conversions to fragment order (10 jobs)
  FJobs J;
  auto job = [&](int i, const float* sA, const float* sB, ushort* d,
                 int NF, int NCT, int P, int mode, int splitVal){
    J.j[i] = {sA, sB, d, NF, NCT, P, mode, splitVal};
  };
  job(0, W_in, nullptr, skipW, 64, 4, 1, 0, 0);
  for (int i = 0; i < 4; ++i)
    job(1 + i, sWl + i * 4096, sWr + i * 4096, sageW + i * 8192, 64, 4, 2, 1, 64);
  job(5, vWl, vWr, yrW,   64, 8, 6, 2, 64);
  job(6, Wmu, Wlv, mulvW, 64, 8, 1, 2, 64);
  job(7, rW1, nullptr, rankW, 64, 4, 1, 0, 0);
  job(8, gW1, nullptr, regW1, 64, 4, 6, 0, 0);
  job(9, gW2, nullptr, regW2, 32, 2, 1, 0, 0);
  k_conv<<<dim3(10, 8), 256, 0, stream>>>(J);

  k_cvt<<<1024, 256, 0, stream>>>(x, xb, NN * 64 / 4);

  const int GB = (NN + 63) / 64;   // 782 row-tile blocks
  k_skip<<<GB, 256, 0, stream>>>(xb, skipW, b_in, skipb);

  const ushort* hprev = xb;
  for (int i = 0; i < 4; ++i){
    k_sage_f<<<GB, 256, 0, stream>>>(hprev, sageW + i * 8192, bsrc16, incnt,
                                     sbl + i * 64, bng + i * 64, bnb + i * 64,
                                     bnm + i * 64, bnv + i * 64, hb[i]);
    hprev = hb[i];
  }

  const int AGG_B = (NN + 3) / 4;   // wave per node, 4 waves/block
  k_agg<<<AGG_B, 256, 0, stream>>>(hb[3], pa, bsrc16, outdeg, incnt, 1);
  k_agg<<<AGG_B, 256, 0, stream>>>(pa, pb, bsrc16, outdeg, incnt, 1);
  k_agg<<<AGG_B, 256, 0, stream>>>(pb, pa, bsrc16, outdeg, incnt, 1);
  k_agg<<<AGG_B, 256, 0, stream>>>(pa, pb, bsrc16, outdeg, incnt, 1);
  // path_out = pb

  k_yr<<<GB, 256, 0, stream>>>(hb[0], hb[1], hb[2], hb[3], skipb, pb, yrW, vbl, Yb, Rb);
  k_mulv_f<<<GB, 256, 0, stream>>>(Yb, Rb, bsrc16, incnt, vg, vbe, vm, vvar,
                                   mulvW, bmu, blv, mu, lv, mub);
  k_rank_m<<<GB, 256, 0, stream>>>(mub, rankW, rb1, rW2, rb2, rank);
  k_reg1<<<GB, 256, 0, stream>>>(hb[0], hb[1], hb[2], hb[3], skipb, mub, rank,
                                 regW1, gW1, gb1, pa);
  k_reg2<<<GB, 256, 0, stream>>>(pa, regW2, gb2, gW3, gb3, preds);
}

// Round 13
// 527.632 us; speedup vs baseline: 1.0723x; 1.0723x over previous
//
#include <hip/hip_runtime.h>
#include <cstdint>
#include <cstddef>

#define NN 50000
#define EE 800000
#define CAP 64
#define EPS_BN 1e-5f

typedef short  s16x8 __attribute__((ext_vector_type(8)));
typedef ushort u16x8 __attribute__((ext_vector_type(8)));
typedef float  f32x4 __attribute__((ext_vector_type(4)));

#define MFMA16(a, b, c) __builtin_amdgcn_mfma_f32_16x16x32_bf16((a), (b), (c), 0, 0, 0)

__device__ inline ushort f2bf(float f){           // round-to-nearest-even fp32->bf16
  uint32_t u = __float_as_uint(f);
  uint32_t r = (u + 0x7FFFu + ((u >> 16) & 1u)) >> 16;
  return (ushort)r;
}
__device__ inline float bf2f(ushort u){ return __uint_as_float((uint32_t)u << 16); }

// ---------------- graph preprocessing ----------------

__global__ void k_outdeg(const int* __restrict__ row, int* __restrict__ outdeg){
  int e = blockIdx.x * blockDim.x + threadIdx.x;
  if (e < EE) atomicAdd(&outdeg[row[e]], 1);
}

__global__ void k_invdeg(const int* __restrict__ outdeg, float* __restrict__ invdeg){
  int n = blockIdx.x * blockDim.x + threadIdx.x;
  if (n < NN) invdeg[n] = 1.0f / fmaxf((float)outdeg[n], 1.0f);
}

// COLUMN-MAJOR bucket: bsrc16[slot*NN + node]. Writes for one slot land in a
// 100KB slice -> hot slices stay L2-resident, 2B writes merge into dirty lines.
__global__ void k_fill(const int* __restrict__ row, const int* __restrict__ col,
                       int* __restrict__ incnt, ushort* __restrict__ bsrc16){
  int e = blockIdx.x * blockDim.x + threadIdx.x;
  if (e >= EE) return;
  int r = row[e], c = col[e];
  int j = atomicAdd(&incnt[c], 1);
  if (j < CAP) bsrc16[(size_t)j * NN + c] = (ushort)r;
}

// ---------------- fp32 -> bf16 bulk convert ----------------

__global__ void k_cvt(const float* __restrict__ src, ushort* __restrict__ dst, int n4){
  int i = blockIdx.x * blockDim.x + threadIdx.x;
  int stride = gridDim.x * blockDim.x;
  for (; i < n4; i += stride){
    float4 v = ((const float4*)src)[i];
    ushort4 u = {f2bf(v.x), f2bf(v.y), f2bf(v.z), f2bf(v.w)};
    ((ushort4*)dst)[i] = u;
  }
}

// ------- weight conversion: fp32 [K x NF] -> bf16 MFMA-fragment order -------
// dst[((ct*P + p)*2 + ks)*512 + lane*8 + j] = W[k][col]
//   col = ct*16 + (lane&15),  k = p*64 + ks*32 + (lane>>4)*8 + j
// mode: 0 = single src; 1 = k-split at splitVal (srcB rows); 2 = col-split.

struct FJob { const float* srcA; const float* srcB; ushort* dst;
              int NF; int NCT; int P; int mode; int splitVal; };
struct FJobs { FJob j[10]; };

__global__ void k_conv(FJobs J){
  FJob jb = J.j[blockIdx.x];
  int total = jb.NCT * jb.P * 1024;
  for (int idx = threadIdx.x + blockIdx.y * 256; idx < total; idx += 256 * gridDim.y){
    int j = idx & 7, lane = (idx >> 3) & 63, ks = (idx >> 9) & 1;
    int rest = idx >> 10;
    int p = rest % jb.P, ct = rest / jb.P;
    int col = ct * 16 + (lane & 15);
    int k   = p * 64 + ks * 32 + (lane >> 4) * 8 + j;
    const float* s = jb.srcA;
    int sc = col, sk = k;
    if (jb.mode == 1 && k   >= jb.splitVal){ s = jb.srcB; sk = k   - jb.splitVal; }
    if (jb.mode == 2 && col >= jb.splitVal){ s = jb.srcB; sc = col - jb.splitVal; }
    jb.dst[idx] = f2bf(s[(size_t)sk * jb.NF + sc]);
  }
}

// ------- aggregation (bf16 in/out): out[c] = sum_e w_e * hin[src_e] --------
// wave per node; 8 lanes x 16B per source row; 16 edges in flight per iter.
// bucket staging: lane j reads bsrc16[j*NN + node] (column-major, L2-resident).
// weights: use_norm ? invdeg[src] : 1/cnt

__global__ void __launch_bounds__(256) k_agg(const ushort* __restrict__ hin,
                                             ushort* __restrict__ out,
                                             const ushort* __restrict__ bsrc16,
                                             const float* __restrict__ invdeg,
                                             const int* __restrict__ incnt,
                                             int use_norm){
  __shared__ int   sidx[4][CAP + 16];
  __shared__ float swgt[4][CAP + 16];
  int wib  = threadIdx.x >> 6;
  int lane = threadIdx.x & 63;
  int wid  = blockIdx.x * 4 + wib;
  bool valid = wid < NN;
  int cnt  = valid ? incnt[wid] : 0;
  int cntb = min(cnt, CAP);
  if (valid){
    int src = (lane < cntb) ? (int)bsrc16[(size_t)lane * NN + wid] : 0;
    float w = 0.f;
    if (lane < cntb)
      w = use_norm ? invdeg[src] : (1.0f / fmaxf((float)cnt, 1.f));
    sidx[wib][lane] = src;
    swgt[wib][lane] = w;
    if (lane < 16){ sidx[wib][CAP + lane] = 0; swgt[wib][CAP + lane] = 0.f; }
  }
  __syncthreads();
  if (!valid) return;

  int g  = lane >> 3;     // edge slot within oct (0..7)
  int fl = lane & 7;      // 16B feature chunk (8 bf16)
  float accf[8] = {0,0,0,0,0,0,0,0};
  for (int e0 = 0; e0 < cntb; e0 += 16){
    int ea = e0 + g, eb = e0 + g + 8;
    int   sa = sidx[wib][ea], sb = sidx[wib][eb];
    float wa = swgt[wib][ea], wb = swgt[wib][eb];
    u16x8 va = *(const u16x8*)(hin + (size_t)sa * 64 + fl * 8);
    u16x8 vb = *(const u16x8*)(hin + (size_t)sb * 64 + fl * 8);
    #pragma unroll
    for (int j = 0; j < 8; ++j){
      accf[j] = fmaf(wa, bf2f(va[j]), accf[j]);
      accf[j] = fmaf(wb, bf2f(vb[j]), accf[j]);
    }
  }
  #pragma unroll
  for (int m = 8; m < 64; m <<= 1){
    #pragma unroll
    for (int j = 0; j < 8; ++j) accf[j] += __shfl_xor(accf[j], m);
  }
  if (lane < 8){
    u16x8 o;
    #pragma unroll
    for (int j = 0; j < 8; ++j) o[j] = f2bf(accf[j]);
    *(u16x8*)(out + (size_t)wid * 64 + lane * 8) = o;
  }
}

// ---------------- direct-load MFMA GEMM (no LDS, no barriers) ----------------
// Wave handles 16 rows. A-frag: 16B global load from bf16 [N][64] row-major at
// row=rowbase+(lane&15), k=(lane>>4)*8. B-frag: contiguous 1KB chunk per
// (ct,p,ks) from fragment-ordered WB.  C/D: col=lane&15, row=(lane>>4)*4+reg.

template<int P, int NCT>
__device__ inline void gemm_direct(const ushort* const* pieces,
                                   const ushort* __restrict__ WB,
                                   int rowbase, f32x4* acc){
  int lane = threadIdx.x & 63;
  int q = lane >> 4, r16 = lane & 15;
  int ar = rowbase + r16; ar = (ar < NN) ? ar : (NN - 1);
  const ushort* wl = WB + lane * 8;
  #pragma unroll
  for (int p = 0; p < P; ++p){
    const ushort* src = pieces[p] + (size_t)ar * 64 + q * 8;
    #pragma unroll
    for (int ks = 0; ks < 2; ++ks){
      s16x8 a = *(const s16x8*)(src + ks * 32);
      #pragma unroll
      for (int ct = 0; ct < NCT; ++ct){
        s16x8 b = *(const s16x8*)(wl + (((ct * P + p) * 2 + ks) << 9));
        acc[ct] = MFMA16(a, b, acc[ct]);
      }
    }
  }
}

// ---- skip = x @ W_in + b_in  (bf16 out) ----
__global__ void __launch_bounds__(256) k_skip(const ushort* __restrict__ xb,
                                              const ushort* __restrict__ WT,
                                              const float* __restrict__ bias,
                                              ushort* __restrict__ outb){
  int lane = threadIdx.x & 63, wv = threadIdx.x >> 6, q = lane >> 4, r16 = lane & 15;
  int rowbase = blockIdx.x * 64 + wv * 16;
  const ushort* pieces[1] = {xb};
  f32x4 acc[4] = {};
  gemm_direct<1, 4>(pieces, WT, rowbase, acc);
  #pragma unroll
  for (int ct = 0; ct < 4; ++ct){
    int col = ct * 16 + r16;
    float b = bias[col];
    #pragma unroll
    for (int r = 0; r < 4; ++r){
      int row = rowbase + q * 4 + r;
      if (row < NN) outb[(size_t)row * 64 + col] = f2bf(acc[ct][r] + b);
    }
  }
}

// ---- sage layer: out = relu(bn([mean|h]@[Wl;Wr] + bl)) + h   (bf16 in/out) ----
__global__ void __launch_bounds__(256) k_sage_m(const ushort* __restrict__ meanb,
                                                const ushort* __restrict__ hb,
                                                const ushort* __restrict__ WT,
                                                const float* __restrict__ bl,
                                                const float* __restrict__ g,
                                                const float* __restrict__ be,
                                                const float* __restrict__ m_,
                                                const float* __restrict__ var_,
                                                ushort* __restrict__ houtb){
  int lane = threadIdx.x & 63, wv = threadIdx.x >> 6, q = lane >> 4, r16 = lane & 15;
  int rowbase = blockIdx.x * 64 + wv * 16;
  const ushort* pieces[2] = {meanb, hb};
  f32x4 acc[4] = {};
  gemm_direct<2, 4>(pieces, WT, rowbase, acc);
  #pragma unroll
  for (int ct = 0; ct < 4; ++ct){
    int col = ct * 16 + r16;
    float sc = g[col] * rsqrtf(var_[col] + EPS_BN);
    float sh = be[col] - m_[col] * sc;
    float bb = bl[col];
    #pragma unroll
    for (int r = 0; r < 4; ++r){
      int row = rowbase + q * 4 + r;
      if (row < NN){
        float t = (acc[ct][r] + bb) * sc + sh;
        float hv = bf2f(hb[(size_t)row * 64 + col]);
        houtb[(size_t)row * 64 + col] = f2bf(fmaxf(t, 0.f) + hv);
      }
    }
  }
}

// ---- YR: [h1..h4|skip|path](384) @ [vWl|vWr] -> Y, R(+vbl)   (bf16 out) ----
__global__ void __launch_bounds__(256) k_yr(const ushort* __restrict__ x0, const ushort* __restrict__ x1,
                                            const ushort* __restrict__ x2, const ushort* __restrict__ x3,
                                            const ushort* __restrict__ x4, const ushort* __restrict__ x5,
                                            const ushort* __restrict__ WT, const float* __restrict__ vbl,
                                            ushort* __restrict__ Y, ushort* __restrict__ R){
  int lane = threadIdx.x & 63, wv = threadIdx.x >> 6, q = lane >> 4, r16 = lane & 15;
  int rowbase = blockIdx.x * 64 + wv * 16;
  const ushort* pieces[6] = {x0, x1, x2, x3, x4, x5};
  f32x4 acc[8] = {};
  gemm_direct<6, 8>(pieces, WT, rowbase, acc);
  #pragma unroll
  for (int ct = 0; ct < 8; ++ct){
    int col = ct * 16 + r16;
    bool isR = col >= 64;
    int c2 = isR ? (col - 64) : col;
    float b = isR ? vbl[c2] : 0.f;
    ushort* dst = isR ? R : Y;
    #pragma unroll
    for (int r = 0; r < 4; ++r){
      int row = rowbase + q * 4 + r;
      if (row < NN) dst[(size_t)row * 64 + c2] = f2bf(acc[ct][r] + b);
    }
  }
}

// ---- mulv: v = relu(bn(Yagg+R)); [mu|lv] = v @ [Wmu|Wlv] + [bmu|blv] ----
__global__ void __launch_bounds__(256) k_mulv_m(const ushort* __restrict__ Yagg,
                                                const ushort* __restrict__ Rb,
                                                const float* __restrict__ vg,
                                                const float* __restrict__ vbe,
                                                const float* __restrict__ vm,
                                                const float* __restrict__ vvar,
                                                const ushort* __restrict__ WT,
                                                const float* __restrict__ bmu,
                                                const float* __restrict__ blv,
                                                float* __restrict__ muf, float* __restrict__ lvf,
                                                ushort* __restrict__ mub){
  __shared__ float ssc[64], ssh[64];
  int t = threadIdx.x;
  if (t < 64){
    float sc = vg[t] * rsqrtf(vvar[t] + EPS_BN);
    ssc[t] = sc; ssh[t] = vbe[t] - vm[t] * sc;
  }
  __syncthreads();
  int lane = t & 63, wv = t >> 6, q = lane >> 4, r16 = lane & 15;
  int rowbase = blockIdx.x * 64 + wv * 16;
  int ar = rowbase + r16; ar = (ar < NN) ? ar : (NN - 1);
  const ushort* wl = WT + lane * 8;
  f32x4 acc[8] = {};
  #pragma unroll
  for (int ks = 0; ks < 2; ++ks){
    int k0 = ks * 32 + q * 8;
    u16x8 y  = *(const u16x8*)(Yagg + (size_t)ar * 64 + k0);
    u16x8 rv = *(const u16x8*)(Rb   + (size_t)ar * 64 + k0);
    s16x8 a;
    #pragma unroll
    for (int j = 0; j < 8; ++j){
      float tv = (bf2f(y[j]) + bf2f(rv[j])) * ssc[k0 + j] + ssh[k0 + j];
      a[j] = (short)f2bf(fmaxf(tv, 0.f));
    }
    #pragma unroll
    for (int ct = 0; ct < 8; ++ct){
      s16x8 b = *(const s16x8*)(wl + (((ct * 1) * 2 + ks) << 9));
      acc[ct] = MFMA16(a, b, acc[ct]);
    }
  }
  #pragma unroll
  for (int ct = 0; ct < 8; ++ct){
    int col = ct * 16 + r16;
    bool isL = col >= 64;
    int c2 = isL ? (col - 64) : col;
    float bb = isL ? blv[c2] : bmu[c2];
    #pragma unroll
    for (int r = 0; r < 4; ++r){
      int row = rowbase + q * 4 + r;
      if (row < NN){
        float v = acc[ct][r] + bb;
        if (isL) lvf[(size_t)row * 64 + c2] = v;
        else { muf[(size_t)row * 64 + c2] = v; mub[(size_t)row * 64 + c2] = f2bf(v); }
      }
    }
  }
}

// ---- rank = relu(mu@rW1+rb1) @ rW2 + rb2 ----
__global__ void __launch_bounds__(256) k_rank_m(const ushort* __restrict__ mub,
                                                const ushort* __restrict__ WT,
                                                const float* __restrict__ rb1,
                                                const float* __restrict__ rW2,
                                                const float* __restrict__ rb2,
                                                float* __restrict__ rout){
  int lane = threadIdx.x & 63, wv = threadIdx.x >> 6, q = lane >> 4, r16 = lane & 15;
  int rowbase = blockIdx.x * 64 + wv * 16;
  const ushort* pieces[1] = {mub};
  f32x4 acc[4] = {};
  gemm_direct<1, 4>(pieces, WT, rowbase, acc);
  float val[4] = {0.f, 0.f, 0.f, 0.f};
  #pragma unroll
  for (int ct = 0; ct < 4; ++ct){
    int col = ct * 16 + r16;
    float b1 = rb1[col], w2 = rW2[col];
    #pragma unroll
    for (int r = 0; r < 4; ++r)
      val[r] += fmaxf(acc[ct][r] + b1, 0.f) * w2;
  }
  #pragma unroll
  for (int r = 0; r < 4; ++r){
    #pragma unroll
    for (int m = 1; m < 16; m <<= 1) val[r] += __shfl_xor(val[r], m);
  }
  if (r16 == 0){
    float b2 = rb2[0];
    #pragma unroll
    for (int r = 0; r < 4; ++r){
      int row = rowbase + q * 4 + r;
      if (row < NN) rout[row] = val[r] + b2;
    }
  }
}

// ---- reg stage 1: h1 = relu([stage1|z](384)@gW1[0:384] + gb1 + rank*gW1[384]) ----
__global__ void __launch_bounds__(256) k_reg1(const ushort* __restrict__ x0, const ushort* __restrict__ x1,
                                              const ushort* __restrict__ x2, const ushort* __restrict__ x3,
                                              const ushort* __restrict__ x4, const ushort* __restrict__ x5,
                                              const float* __restrict__ rank,
                                              const ushort* __restrict__ WT,
                                              const float* __restrict__ gW1,   // fp32, for row 384
                                              const float* __restrict__ gb1,
                                              ushort* __restrict__ h1b){
  int lane = threadIdx.x & 63, wv = threadIdx.x >> 6, q = lane >> 4, r16 = lane & 15;
  int rowbase = blockIdx.x * 64 + wv * 16;
  const ushort* pieces[6] = {x0, x1, x2, x3, x4, x5};
  f32x4 acc[4] = {};
  gemm_direct<6, 4>(pieces, WT, rowbase, acc);
  float rk[4];
  #pragma unroll
  for (int r = 0; r < 4; ++r){
    int row = rowbase + q * 4 + r;
    rk[r] = (row < NN) ? rank[row] : 0.f;
  }
  #pragma unroll
  for (int ct = 0; ct < 4; ++ct){
    int col = ct * 16 + r16;
    float b1 = gb1[col];
    float w384 = gW1[384 * 64 + col];
    #pragma unroll
    for (int r = 0; r < 4; ++r){
      int row = rowbase + q * 4 + r;
      if (row < NN)
        h1b[(size_t)row * 64 + col] = f2bf(fmaxf(acc[ct][r] + b1 + rk[r] * w384, 0.f));
    }
  }
}

// ---- reg tail: h2 = relu(h1@gW2+gb2); preds = h2@gW3 + gb3 ----
__global__ void __launch_bounds__(256) k_reg2(const ushort* __restrict__ h1b,
                                              const ushort* __restrict__ WT,
                                              const float* __restrict__ gb2,
                                              const float* __restrict__ gW3,
                                              const float* __restrict__ gb3,
                                              float* __restrict__ preds){
  int lane = threadIdx.x & 63, wv = threadIdx.x >> 6, q = lane >> 4, r16 = lane & 15;
  int rowbase = blockIdx.x * 64 + wv * 16;
  const ushort* pieces[1] = {h1b};
  f32x4 acc[2] = {};
  gemm_direct<1, 2>(pieces, WT, rowbase, acc);
  float val[4] = {0.f, 0.f, 0.f, 0.f};
  #pragma unroll
  for (int ct = 0; ct < 2; ++ct){
    int col = ct * 16 + r16;       // 0..31
    float b2 = gb2[col], w3 = gW3[col];
    #pragma unroll
    for (int r = 0; r < 4; ++r)
      val[r] += fmaxf(acc[ct][r] + b2, 0.f) * w3;
  }
  #pragma unroll
  for (int r = 0; r < 4; ++r){
    #pragma unroll
    for (int m = 1; m < 16; m <<= 1) val[r] += __shfl_xor(val[r], m);
  }
  if (r16 == 0){
    float b3 = gb3[0];
    #pragma unroll
    for (int r = 0; r < 4; ++r){
      int row = rowbase + q * 4 + r;
      if (row < NN) preds[row] = val[r] + b3;
    }
  }
}

// ---------------- launch ----------------

extern "C" void kernel_launch(void* const* d_in, const int* in_sizes, int n_in,
                              void* d_out, int out_size, void* d_ws, size_t ws_size,
                              hipStream_t stream){
  const float* x    = (const float*)d_in[0];
  const int*   eidx = (const int*)d_in[1];
  const int* row = eidx;
  const int* col = eidx + EE;
  const float* W_in = (const float*)d_in[2];
  const float* b_in = (const float*)d_in[3];
  const float* sWl  = (const float*)d_in[4];
  const float* sbl  = (const float*)d_in[5];
  const float* sWr  = (const float*)d_in[6];
  const float* bng  = (const float*)d_in[7];
  const float* bnb  = (const float*)d_in[8];
  const float* bnm  = (const float*)d_in[9];
  const float* bnv  = (const float*)d_in[10];
  const float* vWl  = (const float*)d_in[11];
  const float* vbl  = (const float*)d_in[12];
  const float* vWr  = (const float*)d_in[13];
  const float* vg   = (const float*)d_in[14];
  const float* vbe  = (const float*)d_in[15];
  const float* vm   = (const float*)d_in[16];
  const float* vvar = (const float*)d_in[17];
  const float* Wmu  = (const float*)d_in[18];
  const float* bmu  = (const float*)d_in[19];
  const float* Wlv  = (const float*)d_in[20];
  const float* blv  = (const float*)d_in[21];
  const float* rW1  = (const float*)d_in[22];
  const float* rb1  = (const float*)d_in[23];
  const float* rW2  = (const float*)d_in[24];
  const float* rb2  = (const float*)d_in[25];
  const float* gW1  = (const float*)d_in[26];
  const float* gb1  = (const float*)d_in[27];
  const float* gW2  = (const float*)d_in[28];
  const float* gb2  = (const float*)d_in[29];
  const float* gW3  = (const float*)d_in[30];
  const float* gb3  = (const float*)d_in[31];

  float* preds = (float*)d_out;
  float* rank  = preds + NN;
  float* mu    = rank + NN;
  float* lv    = mu + (size_t)NN * 64;

  char* w = (char*)d_ws;
  auto alloc = [&](size_t bytes) -> char* {
    char* p = w; w += (bytes + 255) & ~(size_t)255; return p;
  };
  int*    outdeg = (int*)alloc((size_t)NN * 4);
  int*    incnt  = (int*)alloc((size_t)NN * 4);
  float*  invdeg = (float*)alloc((size_t)NN * 4);
  ushort* bsrc16 = (ushort*)alloc((size_t)NN * CAP * 2);
  const size_t FB = (size_t)NN * 64 * 2;           // bf16 feature buffer
  ushort* xb    = (ushort*)alloc(FB);
  ushort* skipb = (ushort*)alloc(FB);
  ushort* hb[4];
  for (int i = 0; i < 4; ++i) hb[i] = (ushort*)alloc(FB);
  ushort* meanb = (ushort*)alloc(FB);
  ushort* pa    = (ushort*)alloc(FB);              // path scratch; reused as h1buf
  ushort* pb    = (ushort*)alloc(FB);
  ushort* Yb    = (ushort*)alloc(FB);
  ushort* Rb    = (ushort*)alloc(FB);
  ushort* mub   = (ushort*)alloc(FB);
  ushort* skipW = (ushort*)alloc(4 * 1024 * 2);        // NCT4 P1
  ushort* sageW = (ushort*)alloc(4 * 8 * 1024 * 2);    // 4 layers x NCT4 P2
  ushort* yrW   = (ushort*)alloc(48 * 1024 * 2);       // NCT8 P6
  ushort* mulvW = (ushort*)alloc(8 * 1024 * 2);        // NCT8 P1
  ushort* rankW = (ushort*)alloc(4 * 1024 * 2);        // NCT4 P1
  ushort* regW1 = (ushort*)alloc(24 * 1024 * 2);       // NCT4 P6
  ushort* regW2 = (ushort*)alloc(2 * 1024 * 2);        // NCT2 P1

  hipMemsetAsync(outdeg, 0, (size_t)NN * 4, stream);
  hipMemsetAsync(incnt,  0, (size_t)NN * 4, stream);

  const int EB = (EE + 255) / 256;
  k_outdeg<<<EB, 256, 0, stream>>>(row, outdeg);
  k_invdeg<<<(NN + 255) / 256, 256, 0, stream>>>(outdeg, invdeg);
  k_fill  <<<EB, 256, 0, stream>>>(row, col, incnt, bsrc16);

  // weight conversions to fragment order (10 jobs)
  FJobs J;
  auto job = [&](int i, const float* sA, const float* sB, ushort* d,
                 int NF, int NCT, int P, int mode, int splitVal){
    J.j[i] = {sA, sB, d, NF, NCT, P, mode, splitVal};
  };
  job(0, W_in, nullptr, skipW, 64, 4, 1, 0, 0);
  for (int i = 0; i < 4; ++i)
    job(1 + i, sWl + i * 4096, sWr + i * 4096, sageW + i * 8192, 64, 4, 2, 1, 64);
  job(5, vWl, vWr, yrW,   64, 8, 6, 2, 64);
  job(6, Wmu, Wlv, mulvW, 64, 8, 1, 2, 64);
  job(7, rW1, nullptr, rankW, 64, 4, 1, 0, 0);
  job(8, gW1, nullptr, regW1, 64, 4, 6, 0, 0);
  job(9, gW2, nullptr, regW2, 32, 2, 1, 0, 0);
  k_conv<<<dim3(10, 8), 256, 0, stream>>>(J);

  k_cvt<<<1024, 256, 0, stream>>>(x, xb, NN * 64 / 4);

  const int GB = (NN + 63) / 64;   // 782 row-tile blocks
  k_skip<<<GB, 256, 0, stream>>>(xb, skipW, b_in, skipb);

  const int AGG_B = (NN + 3) / 4;   // wave per node, 4 waves/block
  const ushort* hprev = xb;
  for (int i = 0; i < 4; ++i){
    k_agg<<<AGG_B, 256, 0, stream>>>(hprev, meanb, bsrc16, invdeg, incnt, 0);
    k_sage_m<<<GB, 256, 0, stream>>>(meanb, hprev, sageW + i * 8192, sbl + i * 64,
                                     bng + i * 64, bnb + i * 64, bnm + i * 64, bnv + i * 64, hb[i]);
    hprev = hb[i];
  }

  k_agg<<<AGG_B, 256, 0, stream>>>(hb[3], pa, bsrc16, invdeg, incnt, 1);
  k_agg<<<AGG_B, 256, 0, stream>>>(pa, pb, bsrc16, invdeg, incnt, 1);
  k_agg<<<AGG_B, 256, 0, stream>>>(pb, pa, bsrc16, invdeg, incnt, 1);
  k_agg<<<AGG_B, 256, 0, stream>>>(pa, pb, bsrc16, invdeg, incnt, 1);
  // path_out = pb

  k_yr<<<GB, 256, 0, stream>>>(hb[0], hb[1], hb[2], hb[3], skipb, pb, yrW, vbl, Yb, Rb);
  k_agg<<<AGG_B, 256, 0, stream>>>(Yb, meanb, bsrc16, invdeg, incnt, 0);
  k_mulv_m<<<GB, 256, 0, stream>>>(meanb, Rb, vg, vbe, vm, vvar, mulvW, bmu, blv, mu, lv, mub);
  k_rank_m<<<GB, 256, 0, stream>>>(mub, rankW, rb1, rW2, rb2, rank);
  k_reg1<<<GB, 256, 0, stream>>>(hb[0], hb[1], hb[2], hb[3], skipb, mub, rank,
                                 regW1, gW1, gb1, pa);
  k_reg2<<<GB, 256, 0, stream>>>(pa, regW2, gb2, gW3, gb3, preds);
}